// Round 1
// baseline (17.784 us; speedup 1.0000x reference)
//
#include <hip/hip_runtime.h>
#include <math.h>

#define THREADS 256

// One thread per (b,w) position. F=8 features, D=8 channels, OUT=8.
// Fused algebra:
//   logits_f = (h_f . wkq + bkq) / sqrt(8),  wkq = Wk^T qv, bkq = bk.qv
//   out      = M . (softmax-weighted mean of h_f) + c,  M = P O Wv,
//   c        = P (O bv + ob) + pb
__global__ __launch_bounds__(THREADS) void misstsm_fused(
    const float* __restrict__ x, const int* __restrict__ m,
    const float* __restrict__ emb_w, const float* __restrict__ emb_b,
    const float* __restrict__ emb_ln_g, const float* __restrict__ emb_ln_b,
    const float* __restrict__ ln_g, const float* __restrict__ ln_b,
    const float* __restrict__ var_query,
    const float* __restrict__ in_proj_w, const float* __restrict__ in_proj_b,
    const float* __restrict__ out_proj_w, const float* __restrict__ out_proj_b,
    const float* __restrict__ proj_w, const float* __restrict__ proj_b,
    float* __restrict__ out, int npos)
{
    __shared__ float s_qv[8], s_tv[8], s_PO[64];
    __shared__ float s_M[64];
    __shared__ float s_c[8], s_wkq[8], s_bkq[1];
    __shared__ float s_ey[8][4];
    __shared__ float s_ew[8], s_eb[8], s_eg[8], s_eB[8], s_lg[8], s_lB[8];

    const int t = threadIdx.x;

    // ---- per-block precompute (64 threads), stage 1 ----
    if (t < 64) {
        const int p = t >> 3, e = t & 7;
        float acc = 0.0f;
        #pragma unroll
        for (int o = 0; o < 8; ++o) acc += proj_w[p*8+o] * out_proj_w[o*8+e];
        s_PO[t] = acc;                         // (P O)[p][e]
        if (t < 8) {
            float q = in_proj_b[t];
            #pragma unroll
            for (int d = 0; d < 8; ++d) q += in_proj_w[t*8+d] * var_query[d];
            s_qv[t] = q;                       // qv = Wq vq + bq
            float tv = out_proj_b[t];
            #pragma unroll
            for (int e2 = 0; e2 < 8; ++e2) tv += out_proj_w[t*8+e2] * in_proj_b[16+e2];
            s_tv[t] = tv;                      // O bv + ob
            s_ew[t] = emb_w[t];   s_eb[t] = emb_b[t];
            s_eg[t] = emb_ln_g[t]; s_eB[t] = emb_ln_b[t];
            s_lg[t] = ln_g[t];    s_lB[t] = ln_b[t];
            const float ff = (float)t;         // emb_y for f = t
            s_ey[t][0] = sinf(ff);
            s_ey[t][1] = cosf(ff);
            s_ey[t][2] = sinf(0.01f*ff);
            s_ey[t][3] = cosf(0.01f*ff);
        }
    }
    __syncthreads();
    // ---- stage 2 ----
    if (t < 64) {
        const int p = t >> 3, d = t & 7;
        float acc = 0.0f;
        #pragma unroll
        for (int e = 0; e < 8; ++e) acc += s_PO[p*8+e] * in_proj_w[(16+e)*8 + d];
        s_M[t] = acc;                          // M = (P O) Wv
        if (t < 8) {
            float wk = 0.0f;
            #pragma unroll
            for (int e = 0; e < 8; ++e) wk += in_proj_w[(8+e)*8 + t] * s_qv[e];
            s_wkq[t] = wk;                     // Wk^T qv
            float cc = proj_b[t];
            #pragma unroll
            for (int o = 0; o < 8; ++o) cc += proj_w[t*8+o] * s_tv[o];
            s_c[t] = cc;                       // P (O bv + ob) + pb
            if (t == 0) {
                float bk = 0.0f;
                #pragma unroll
                for (int e = 0; e < 8; ++e) bk += in_proj_b[8+e] * s_qv[e];
                s_bkq[0] = bk;                 // bk . qv
            }
        }
    }
    __syncthreads();

    const int pos = blockIdx.x * THREADS + t;
    if (pos >= npos) return;
    const int w = pos & 2047;                  // W = 2048

    const float4* xv4 = reinterpret_cast<const float4*>(x);
    const int4*   mv4 = reinterpret_cast<const int4*>(m);
    const float4 xa = xv4[pos*2+0];
    const float4 xb = xv4[pos*2+1];
    const int4   ma = mv4[pos*2+0];
    const int4   mb = mv4[pos*2+1];
    const float xf[8] = {xa.x, xa.y, xa.z, xa.w, xb.x, xb.y, xb.z, xb.w};
    const int mk = (ma.x!=0?1:0) | (ma.y!=0?2:0) | (ma.z!=0?4:0) | (ma.w!=0?8:0)
                 | (mb.x!=0?16:0) | (mb.y!=0?32:0) | (mb.z!=0?64:0) | (mb.w!=0?128:0);

    // pos-enc x-part (depends on w only): [sin w, cos w, sin .01w, cos .01w]
    const float fw = (float)w;
    const float px0 = sinf(fw), px1 = cosf(fw);
    const float px2 = sinf(0.01f*fw), px3 = cosf(0.01f*fw);

    float run_max = -INFINITY, run_sum = 0.0f;
    float hb[8];
    #pragma unroll
    for (int d = 0; d < 8; ++d) hb[d] = 0.0f;

    #pragma unroll
    for (int f = 0; f < 8; ++f) {
        float h[8];
        const float xs = xf[f];
        #pragma unroll
        for (int d = 0; d < 8; ++d) h[d] = xs * s_ew[d] + s_eb[d];
        // LayerNorm 1 (emb_ln)
        float mu = 0.0f;
        #pragma unroll
        for (int d = 0; d < 8; ++d) mu += h[d];
        mu *= 0.125f;
        float var = 0.0f;
        #pragma unroll
        for (int d = 0; d < 8; ++d) { const float z = h[d]-mu; var += z*z; }
        var *= 0.125f;
        const float r = rsqrtf(var + 1e-5f);
        #pragma unroll
        for (int d = 0; d < 8; ++d) h[d] = (h[d]-mu)*r*s_eg[d] + s_eB[d];
        // + 2D positional encoding
        h[0]+=px0; h[1]+=px1; h[2]+=px2; h[3]+=px3;
        h[4]+=s_ey[f][0]; h[5]+=s_ey[f][1]; h[6]+=s_ey[f][2]; h[7]+=s_ey[f][3];
        // LayerNorm 2 (ln)
        float mu2 = 0.0f;
        #pragma unroll
        for (int d = 0; d < 8; ++d) mu2 += h[d];
        mu2 *= 0.125f;
        float var2 = 0.0f;
        #pragma unroll
        for (int d = 0; d < 8; ++d) { const float z = h[d]-mu2; var2 += z*z; }
        var2 *= 0.125f;
        const float r2 = rsqrtf(var2 + 1e-5f);
        #pragma unroll
        for (int d = 0; d < 8; ++d) h[d] = (h[d]-mu2)*r2*s_lg[d] + s_lB[d];

        // logit + online softmax accumulation of h-bar
        float l = s_bkq[0];
        #pragma unroll
        for (int d = 0; d < 8; ++d) l += h[d]*s_wkq[d];
        l *= 0.35355339059327373f;   // 1/sqrt(8)

        if (!((mk >> f) & 1)) {
            const float nM = fmaxf(run_max, l);
            const float sc = __expf(run_max - nM);  // first hit: exp(-inf)=0
            const float pp = __expf(l - nM);
            run_sum = run_sum * sc + pp;
            #pragma unroll
            for (int d = 0; d < 8; ++d) hb[d] = hb[d]*sc + pp*h[d];
            run_max = nM;
        }
    }

    const float inv = 1.0f / run_sum;
    #pragma unroll
    for (int d = 0; d < 8; ++d) hb[d] *= inv;

    float o[8];
    #pragma unroll
    for (int p = 0; p < 8; ++p) {
        float acc = s_c[p];
        #pragma unroll
        for (int d = 0; d < 8; ++d) acc += s_M[p*8+d]*hb[d];
        o[p] = acc;
    }
    float4* ov4 = reinterpret_cast<float4*>(out);
    ov4[pos*2+0] = make_float4(o[0], o[1], o[2], o[3]);
    ov4[pos*2+1] = make_float4(o[4], o[5], o[6], o[7]);
}

extern "C" void kernel_launch(void* const* d_in, const int* in_sizes, int n_in,
                              void* d_out, int out_size, void* d_ws, size_t ws_size,
                              hipStream_t stream) {
    const float* x          = (const float*)d_in[0];
    const int*   m          = (const int*)d_in[1];
    const float* emb_w      = (const float*)d_in[2];
    const float* emb_b      = (const float*)d_in[3];
    const float* emb_ln_g   = (const float*)d_in[4];
    const float* emb_ln_b   = (const float*)d_in[5];
    const float* ln_g       = (const float*)d_in[6];
    const float* ln_b       = (const float*)d_in[7];
    const float* var_query  = (const float*)d_in[8];
    const float* in_proj_w  = (const float*)d_in[9];
    const float* in_proj_b  = (const float*)d_in[10];
    const float* out_proj_w = (const float*)d_in[11];
    const float* out_proj_b = (const float*)d_in[12];
    const float* proj_w     = (const float*)d_in[13];
    const float* proj_b     = (const float*)d_in[14];
    float* out = (float*)d_out;

    const int npos = in_sizes[0] / 8;               // B*W = 262144
    const int grid = (npos + THREADS - 1) / THREADS; // 1024 blocks
    misstsm_fused<<<grid, THREADS, 0, stream>>>(
        x, m, emb_w, emb_b, emb_ln_g, emb_ln_b, ln_g, ln_b, var_query,
        in_proj_w, in_proj_b, out_proj_w, out_proj_b, proj_w, proj_b,
        out, npos);
}

// Round 2
// 17.115 us; speedup vs baseline: 1.0391x; 1.0391x over previous
//
#include <hip/hip_runtime.h>
#include <math.h>

#define THREADS 256
#define W_DIM 2048
#define INV_SQRT8 0.35355339059327373f

// d_ws float layout (cb):
//   0-7    a[d]    = (emb_w[d]-mean)*emb_ln_g[d]
//   8-15   bb[d]   = (emb_b[d]-mean)*emb_ln_g[d]
//   16-23  wlg[d]  = ln_g[d]*wkq[d]*inv_sqrt8
//   24-55  Bf[f][j]= emb_ln_b[4+j] + emb_y(f)[j]          (32)
//   56-63  Mr[p]   = sum_d M'[p][d]
//   64-127 M'[p][d]= (P O Wv)[p][d]*ln_g[d]               (64)
//   128-135 c2[p]  = c[p] + sum_d M[p][d]*ln_b[d]
//   136 A  137 twoB  138 Cc+eps  139 swlg  140 cK
//   144+   table float4[2048]: {emb_ln_b[j] + emb_x(w)[j]} j=0..3

__global__ __launch_bounds__(256) void misstsm_pre(
    const float* __restrict__ emb_w, const float* __restrict__ emb_b,
    const float* __restrict__ emb_ln_g, const float* __restrict__ emb_ln_b,
    const float* __restrict__ ln_g, const float* __restrict__ ln_b,
    const float* __restrict__ var_query,
    const float* __restrict__ in_proj_w, const float* __restrict__ in_proj_b,
    const float* __restrict__ out_proj_w, const float* __restrict__ out_proj_b,
    const float* __restrict__ proj_w, const float* __restrict__ proj_b,
    float* __restrict__ cb)
{
    const int t = threadIdx.x;
    const int g = blockIdx.x * 256 + t;
    if (g < W_DIM) {                       // 8 blocks x 256 = 2048 exactly
        const float fw = (float)g;
        float4 px;
        px.x = emb_ln_b[0] + sinf(fw);
        px.y = emb_ln_b[1] + cosf(fw);
        px.z = emb_ln_b[2] + sinf(0.01f * fw);
        px.w = emb_ln_b[3] + cosf(0.01f * fw);
        reinterpret_cast<float4*>(cb + 144)[g] = px;
    }
    if (blockIdx.x != 0) return;

    __shared__ float s_qv[8], s_tv[8], s_PO[64], s_M[64], s_wkq[8], s_c[8];

    if (t < 64) {
        const int p = t >> 3, e = t & 7;
        float acc = 0.0f;
        #pragma unroll
        for (int o = 0; o < 8; ++o) acc += proj_w[p*8+o] * out_proj_w[o*8+e];
        s_PO[t] = acc;                                   // (P O)[p][e]
        if (t < 8) {
            float q = in_proj_b[t];
            #pragma unroll
            for (int d = 0; d < 8; ++d) q += in_proj_w[t*8+d] * var_query[d];
            s_qv[t] = q;                                 // Wq vq + bq
            float tv = out_proj_b[t];
            #pragma unroll
            for (int e2 = 0; e2 < 8; ++e2) tv += out_proj_w[t*8+e2] * in_proj_b[16+e2];
            s_tv[t] = tv;                                // O bv + ob
        }
    }
    __syncthreads();
    if (t < 64) {
        const int p = t >> 3, d = t & 7;
        float acc = 0.0f;
        #pragma unroll
        for (int e = 0; e < 8; ++e) acc += s_PO[p*8+e] * in_proj_w[(16+e)*8 + d];
        s_M[t] = acc;                                    // M = (P O) Wv
        if (t < 8) {
            float wk = 0.0f;
            #pragma unroll
            for (int e = 0; e < 8; ++e) wk += in_proj_w[(8+e)*8 + t] * s_qv[e];
            s_wkq[t] = wk;                               // Wk^T qv
            float cc = proj_b[t];
            #pragma unroll
            for (int o = 0; o < 8; ++o) cc += proj_w[t*8+o] * s_tv[o];
            s_c[t] = cc;                                 // P (O bv + ob) + pb
        }
    }
    __syncthreads();

    if (t < 64) {
        const int p = t >> 3, d = t & 7;
        cb[64 + t] = s_M[t] * ln_g[d];                   // M'
    }
    if (t < 32) {                                        // Bf[f][j]
        const int f = t >> 2, j = t & 3;
        const float ff = (float)f;
        float tr;
        if      (j == 0) tr = sinf(ff);
        else if (j == 1) tr = cosf(ff);
        else if (j == 2) tr = sinf(0.01f * ff);
        else             tr = cosf(0.01f * ff);
        cb[24 + t] = emb_ln_b[4 + j] + tr;
    }
    if (t < 8) {
        float ewm = 0.0f, ebm = 0.0f;
        #pragma unroll
        for (int d = 0; d < 8; ++d) { ewm += emb_w[d]; ebm += emb_b[d]; }
        ewm *= 0.125f; ebm *= 0.125f;
        const float dew = emb_w[t] - ewm, deb = emb_b[t] - ebm;
        cb[t]      = dew * emb_ln_g[t];                  // a
        cb[8 + t]  = deb * emb_ln_g[t];                  // bb
        cb[16 + t] = ln_g[t] * s_wkq[t] * INV_SQRT8;     // wlg (scaled)
        float mr = 0.0f, cl = 0.0f;
        #pragma unroll
        for (int d = 0; d < 8; ++d) {
            mr += s_M[t*8 + d] * ln_g[d];
            cl += s_M[t*8 + d] * ln_b[d];
        }
        cb[56 + t]  = mr;                                // Mr
        cb[128 + t] = s_c[t] + cl;                       // c2
        if (t == 0) {
            float A = 0.0f, Bc = 0.0f, Cc = 0.0f, swlg = 0.0f, ckd = 0.0f, bkq = 0.0f;
            #pragma unroll
            for (int d = 0; d < 8; ++d) {
                const float dw = emb_w[d] - ewm, db = emb_b[d] - ebm;
                A  += dw * dw; Bc += dw * db; Cc += db * db;
                swlg += ln_g[d] * s_wkq[d];
                ckd  += ln_b[d] * s_wkq[d];
                bkq  += in_proj_b[8 + d] * s_qv[d];
            }
            cb[136] = A * 0.125f;
            cb[137] = 2.0f * Bc * 0.125f;
            cb[138] = Cc * 0.125f + 1e-5f;
            cb[139] = swlg * INV_SQRT8;
            cb[140] = (ckd + bkq) * INV_SQRT8;
        }
    }
}

__global__ __launch_bounds__(THREADS) void misstsm_main(
    const float* __restrict__ x, const int* __restrict__ m,
    const float* __restrict__ cb, float* __restrict__ out, int npos)
{
    const int pos = blockIdx.x * THREADS + threadIdx.x;
    if (pos >= npos) return;
    const int w = pos & (W_DIM - 1);

    const float4* xv4 = reinterpret_cast<const float4*>(x);
    const int4*   mv4 = reinterpret_cast<const int4*>(m);
    const float4 xa = xv4[pos*2+0];
    const float4 xb = xv4[pos*2+1];
    const int4   ma = mv4[pos*2+0];
    const int4   mb = mv4[pos*2+1];
    const float4 pw = reinterpret_cast<const float4*>(cb + 144)[w];

    const float xf[8] = {xa.x, xa.y, xa.z, xa.w, xb.x, xb.y, xb.z, xb.w};
    const float pB[4] = {pw.x, pw.y, pw.z, pw.w};
    const int mk = (ma.x!=0?1:0) | (ma.y!=0?2:0) | (ma.z!=0?4:0) | (ma.w!=0?8:0)
                 | (mb.x!=0?16:0) | (mb.y!=0?32:0) | (mb.z!=0?64:0) | (mb.w!=0?128:0);

    const float A    = cb[136];
    const float twoB = cb[137];
    const float Cc   = cb[138];
    const float swlg = cb[139];
    const float cK   = cb[140];

    float av[8];
    #pragma unroll
    for (int d = 0; d < 8; ++d) av[d] = 0.0f;
    float S = 0.0f, smu = 0.0f;

    #pragma unroll
    for (int f = 0; f < 8; ++f) {
        const float xs = xf[f];
        // LN1 in closed form: var = xs^2 A + 2 xs B + C (+eps folded)
        const float r  = rsqrtf(fmaf(xs, fmaf(xs, A, twoB), Cc));
        const float tt = xs * r;
        // v[d] = LN1out[d] + pos[d] = tt*a[d] + r*bb[d] + B[d]
        float v[8];
        #pragma unroll
        for (int j = 0; j < 4; ++j)
            v[j] = fmaf(tt, cb[j], fmaf(r, cb[8+j], pB[j]));
        #pragma unroll
        for (int j = 0; j < 4; ++j)
            v[4+j] = fmaf(tt, cb[4+j], fmaf(r, cb[12+j], cb[24 + f*4 + j]));
        // LN2 stats + logit dot in one pass
        float sv = 0.0f, s2 = 0.0f, dt = 0.0f;
        #pragma unroll
        for (int d = 0; d < 8; ++d) {
            sv += v[d];
            s2  = fmaf(v[d], v[d], s2);
            dt  = fmaf(v[d], cb[16+d], dt);
        }
        const float mu  = sv * 0.125f;
        const float var = fmaf(-mu, mu, fmaf(s2, 0.125f, 1e-5f));
        const float r2  = rsqrtf(var);
        const float l   = fmaf(r2, fmaf(-mu, swlg, dt), cK);   // already /sqrt(8)
        const float e   = __expf(l);                           // logits tiny: no max needed
        const float pp  = ((mk >> f) & 1) ? 0.0f : e;
        S += pp;
        const float cf = pp * r2;
        #pragma unroll
        for (int d = 0; d < 8; ++d) av[d] = fmaf(cf, v[d], av[d]);
        smu = fmaf(cf, mu, smu);
    }

    const float invS = 1.0f / S;
    float o[8];
    #pragma unroll
    for (int p = 0; p < 8; ++p) {
        float dp = 0.0f;
        #pragma unroll
        for (int d = 0; d < 8; ++d) dp = fmaf(cb[64 + p*8 + d], av[d], dp);
        dp = fmaf(-smu, cb[56 + p], dp);
        o[p] = fmaf(invS, dp, cb[128 + p]);
    }
    float4* ov4 = reinterpret_cast<float4*>(out);
    ov4[pos*2+0] = make_float4(o[0], o[1], o[2], o[3]);
    ov4[pos*2+1] = make_float4(o[4], o[5], o[6], o[7]);
}

extern "C" void kernel_launch(void* const* d_in, const int* in_sizes, int n_in,
                              void* d_out, int out_size, void* d_ws, size_t ws_size,
                              hipStream_t stream) {
    const float* x          = (const float*)d_in[0];
    const int*   m          = (const int*)d_in[1];
    const float* emb_w      = (const float*)d_in[2];
    const float* emb_b      = (const float*)d_in[3];
    const float* emb_ln_g   = (const float*)d_in[4];
    const float* emb_ln_b   = (const float*)d_in[5];
    const float* ln_g       = (const float*)d_in[6];
    const float* ln_b       = (const float*)d_in[7];
    const float* var_query  = (const float*)d_in[8];
    const float* in_proj_w  = (const float*)d_in[9];
    const float* in_proj_b  = (const float*)d_in[10];
    const float* out_proj_w = (const float*)d_in[11];
    const float* out_proj_b = (const float*)d_in[12];
    const float* proj_w     = (const float*)d_in[13];
    const float* proj_b     = (const float*)d_in[14];
    float* out = (float*)d_out;
    float* cb  = (float*)d_ws;

    const int npos = in_sizes[0] / 8;                 // B*W = 262144
    misstsm_pre<<<8, 256, 0, stream>>>(
        emb_w, emb_b, emb_ln_g, emb_ln_b, ln_g, ln_b, var_query,
        in_proj_w, in_proj_b, out_proj_w, out_proj_b, proj_w, proj_b, cb);
    const int grid = (npos + THREADS - 1) / THREADS;  // 1024 blocks
    misstsm_main<<<grid, THREADS, 0, stream>>>(x, m, cb, out, npos);
}

// Round 3
// 15.996 us; speedup vs baseline: 1.1118x; 1.0700x over previous
//
#include <hip/hip_runtime.h>
#include <math.h>

#define THREADS 256
#define W_DIM 2048
#define INV_SQRT8 0.35355339059327373f

// Single fused kernel. Per-block precompute (one __syncthreads) of all
// folded constants into LDS, then one thread per (b,w) position.
// Algebra:
//   LN1 closed form: h = xs*ew+eb  =>  var = xs^2*A + 2*xs*B + C
//   v[d] = tt*a[d] + r*bb[d] + pos[d]   (tt = xs*r, r = rsqrt(var+eps))
//   logit = r2*(v.wlg - mu*swlg) + cK   (already /sqrt(8))
//   out[p] = invS * sum_d M[p][d]*lg[d]*(av[d]-smu) + c2[p]
__global__ __launch_bounds__(THREADS) void misstsm_fused(
    const float* __restrict__ x, const int* __restrict__ m,
    const float* __restrict__ emb_w, const float* __restrict__ emb_b,
    const float* __restrict__ emb_ln_g, const float* __restrict__ emb_ln_b,
    const float* __restrict__ ln_g, const float* __restrict__ ln_b,
    const float* __restrict__ var_query,
    const float* __restrict__ in_proj_w, const float* __restrict__ in_proj_b,
    const float* __restrict__ out_proj_w, const float* __restrict__ out_proj_b,
    const float* __restrict__ proj_w, const float* __restrict__ proj_b,
    float* __restrict__ out, int npos)
{
    __shared__ float s_M[64];     // M[p][d] = (P O Wv)[p][d]
    __shared__ float s_c2[8];     // c2[p]
    __shared__ float s_a[8], s_bb[8], s_wlg[8], s_lg[8];
    __shared__ float s_Bf[32];    // emb_ln_b[4+j] + emb_y(f)[j]
    __shared__ float s_sc[5];     // A, twoB, Cc+eps, swlg, cK

    const int t = threadIdx.x;

    // ---- per-block precompute: all tasks independent, ONE sync ----
    if (t < 64) {
        const int p = t >> 3, d = t & 7;
        float acc = 0.0f;
        #pragma unroll
        for (int e = 0; e < 8; ++e) {
            float po = 0.0f;
            #pragma unroll
            for (int o = 0; o < 8; ++o) po = fmaf(proj_w[p*8+o], out_proj_w[o*8+e], po);
            acc = fmaf(po, in_proj_w[(16+e)*8 + d], acc);
        }
        s_M[t] = acc;
    } else if (t < 72) {          // wlg[d] (needs wkq[d] -> inline qv)
        const int d = t - 64;
        float wk = 0.0f;
        #pragma unroll
        for (int e = 0; e < 8; ++e) {
            float qe = in_proj_b[e];
            #pragma unroll
            for (int dd = 0; dd < 8; ++dd) qe = fmaf(in_proj_w[e*8+dd], var_query[dd], qe);
            wk = fmaf(in_proj_w[(8+e)*8 + d], qe, wk);
        }
        s_wlg[d] = ln_g[d] * wk * INV_SQRT8;
        s_lg[d]  = ln_g[d];
    } else if (t < 80) {          // a[d], bb[d]
        const int d = t - 72;
        float ewm = 0.0f, ebm = 0.0f;
        #pragma unroll
        for (int dd = 0; dd < 8; ++dd) { ewm += emb_w[dd]; ebm += emb_b[dd]; }
        ewm *= 0.125f; ebm *= 0.125f;
        s_a[d]  = (emb_w[d] - ewm) * emb_ln_g[d];
        s_bb[d] = (emb_b[d] - ebm) * emb_ln_g[d];
    } else if (t < 88) {          // c2[p]
        const int p = t - 80;
        float c = proj_b[p];
        #pragma unroll
        for (int o = 0; o < 8; ++o) {
            float ob2 = out_proj_b[o];
            #pragma unroll
            for (int e = 0; e < 8; ++e) ob2 = fmaf(out_proj_w[o*8+e], in_proj_b[16+e], ob2);
            c = fmaf(proj_w[p*8+o], ob2, c);
        }
        #pragma unroll
        for (int e = 0; e < 8; ++e) {
            float po = 0.0f;
            #pragma unroll
            for (int o = 0; o < 8; ++o) po = fmaf(proj_w[p*8+o], out_proj_w[o*8+e], po);
            #pragma unroll
            for (int d = 0; d < 8; ++d)
                c = fmaf(po * in_proj_w[(16+e)*8 + d], ln_b[d], c);
        }
        s_c2[p] = c;
    } else if (t < 120) {         // Bf[f][j]
        const int k = t - 88, f = k >> 2, j = k & 3;
        const float ff = (float)f;
        float tr;
        if      (j == 0) tr = sinf(ff);
        else if (j == 1) tr = cosf(ff);
        else if (j == 2) tr = sinf(0.01f * ff);
        else             tr = cosf(0.01f * ff);
        s_Bf[k] = emb_ln_b[4 + j] + tr;
    } else if (t == 120) {        // A, twoB, Cc
        float ewm = 0.0f, ebm = 0.0f;
        #pragma unroll
        for (int d = 0; d < 8; ++d) { ewm += emb_w[d]; ebm += emb_b[d]; }
        ewm *= 0.125f; ebm *= 0.125f;
        float A = 0.0f, Bc = 0.0f, Cc = 0.0f;
        #pragma unroll
        for (int d = 0; d < 8; ++d) {
            const float dw = emb_w[d] - ewm, db = emb_b[d] - ebm;
            A = fmaf(dw, dw, A); Bc = fmaf(dw, db, Bc); Cc = fmaf(db, db, Cc);
        }
        s_sc[0] = A * 0.125f;
        s_sc[1] = 2.0f * Bc * 0.125f;
        s_sc[2] = Cc * 0.125f + 1e-5f;
    } else if (t == 121) {        // swlg, cK
        float qv[8];
        float bkq = 0.0f;
        #pragma unroll
        for (int e = 0; e < 8; ++e) {
            float qe = in_proj_b[e];
            #pragma unroll
            for (int dd = 0; dd < 8; ++dd) qe = fmaf(in_proj_w[e*8+dd], var_query[dd], qe);
            qv[e] = qe;
            bkq = fmaf(in_proj_b[8+e], qe, bkq);
        }
        float swlg = 0.0f, ckd = 0.0f;
        #pragma unroll
        for (int d = 0; d < 8; ++d) {
            float wk = 0.0f;
            #pragma unroll
            for (int e = 0; e < 8; ++e) wk = fmaf(in_proj_w[(8+e)*8 + d], qv[e], wk);
            swlg = fmaf(ln_g[d], wk, swlg);
            ckd  = fmaf(ln_b[d], wk, ckd);
        }
        s_sc[3] = swlg * INV_SQRT8;
        s_sc[4] = (ckd + bkq) * INV_SQRT8;
    }
    __syncthreads();

    const int pos = blockIdx.x * THREADS + t;
    if (pos >= npos) return;
    const int w = pos & (W_DIM - 1);

    const float4* xv4 = reinterpret_cast<const float4*>(x);
    const int4*   mv4 = reinterpret_cast<const int4*>(m);
    const float4 xa = xv4[pos*2+0];
    const float4 xb = xv4[pos*2+1];
    const int4   ma = mv4[pos*2+0];
    const int4   mb = mv4[pos*2+1];

    const float xf[8] = {xa.x, xa.y, xa.z, xa.w, xb.x, xb.y, xb.z, xb.w};
    const int mk = (ma.x!=0?1:0) | (ma.y!=0?2:0) | (ma.z!=0?4:0) | (ma.w!=0?8:0)
                 | (mb.x!=0?16:0) | (mb.y!=0?32:0) | (mb.z!=0?64:0) | (mb.w!=0?128:0);

    // w-dependent pos-enc (emb_ln_b[0..3] folded in)
    const float fw = (float)w;
    float pB[4];
    pB[0] = emb_ln_b[0] + sinf(fw);
    pB[1] = emb_ln_b[1] + cosf(fw);
    pB[2] = emb_ln_b[2] + sinf(0.01f * fw);
    pB[3] = emb_ln_b[3] + cosf(0.01f * fw);

    const float A    = s_sc[0];
    const float twoB = s_sc[1];
    const float Cc   = s_sc[2];
    const float swlg = s_sc[3];
    const float cK   = s_sc[4];

    float av[8];
    #pragma unroll
    for (int d = 0; d < 8; ++d) av[d] = 0.0f;
    float S = 0.0f, smu = 0.0f;

    #pragma unroll
    for (int f = 0; f < 8; ++f) {
        const float xs = xf[f];
        const float r  = rsqrtf(fmaf(xs, fmaf(xs, A, twoB), Cc));
        const float tt = xs * r;
        float v[8];
        #pragma unroll
        for (int j = 0; j < 4; ++j)
            v[j] = fmaf(tt, s_a[j], fmaf(r, s_bb[j], pB[j]));
        #pragma unroll
        for (int j = 0; j < 4; ++j)
            v[4+j] = fmaf(tt, s_a[4+j], fmaf(r, s_bb[4+j], s_Bf[f*4 + j]));
        float sv = 0.0f, s2 = 0.0f, dt = 0.0f;
        #pragma unroll
        for (int d = 0; d < 8; ++d) {
            sv += v[d];
            s2  = fmaf(v[d], v[d], s2);
            dt  = fmaf(v[d], s_wlg[d], dt);
        }
        const float mu  = sv * 0.125f;
        const float var = fmaf(-mu, mu, fmaf(s2, 0.125f, 1e-5f));
        const float r2  = rsqrtf(var);
        const float l   = fmaf(r2, fmaf(-mu, swlg, dt), cK);
        const float e   = __expf(l);           // logits tiny; no running max
        const float pp  = ((mk >> f) & 1) ? 0.0f : e;
        S += pp;
        const float cf = pp * r2;
        #pragma unroll
        for (int d = 0; d < 8; ++d) av[d] = fmaf(cf, v[d], av[d]);
        smu = fmaf(cf, mu, smu);
    }

    const float invS = 1.0f / S;
    float q[8];
    #pragma unroll
    for (int d = 0; d < 8; ++d) q[d] = s_lg[d] * invS * (av[d] - smu);

    float o[8];
    #pragma unroll
    for (int p = 0; p < 8; ++p) {
        float dp = s_c2[p];
        #pragma unroll
        for (int d = 0; d < 8; ++d) dp = fmaf(s_M[p*8+d], q[d], dp);
        o[p] = dp;
    }
    float4* ov4 = reinterpret_cast<float4*>(out);
    ov4[pos*2+0] = make_float4(o[0], o[1], o[2], o[3]);
    ov4[pos*2+1] = make_float4(o[4], o[5], o[6], o[7]);
}

extern "C" void kernel_launch(void* const* d_in, const int* in_sizes, int n_in,
                              void* d_out, int out_size, void* d_ws, size_t ws_size,
                              hipStream_t stream) {
    const float* x          = (const float*)d_in[0];
    const int*   m          = (const int*)d_in[1];
    const float* emb_w      = (const float*)d_in[2];
    const float* emb_b      = (const float*)d_in[3];
    const float* emb_ln_g   = (const float*)d_in[4];
    const float* emb_ln_b   = (const float*)d_in[5];
    const float* ln_g       = (const float*)d_in[6];
    const float* ln_b       = (const float*)d_in[7];
    const float* var_query  = (const float*)d_in[8];
    const float* in_proj_w  = (const float*)d_in[9];
    const float* in_proj_b  = (const float*)d_in[10];
    const float* out_proj_w = (const float*)d_in[11];
    const float* out_proj_b = (const float*)d_in[12];
    const float* proj_w     = (const float*)d_in[13];
    const float* proj_b     = (const float*)d_in[14];
    float* out = (float*)d_out;

    const int npos = in_sizes[0] / 8;                 // B*W = 262144
    const int grid = (npos + THREADS - 1) / THREADS;  // 1024 blocks
    misstsm_fused<<<grid, THREADS, 0, stream>>>(
        x, m, emb_w, emb_b, emb_ln_g, emb_ln_b, ln_g, ln_b, var_query,
        in_proj_w, in_proj_b, out_proj_w, out_proj_b, proj_w, proj_b,
        out, npos);
}

// Round 4
// 13.931 us; speedup vs baseline: 1.2766x; 1.1482x over previous
//
#include <hip/hip_runtime.h>
#include <math.h>

#define THREADS 256
#define W_DIM 2048
#define INV_SQRT8 0.35355339059327373f

// Fully scalar-decomposed fused kernel.
//   LN1 closed form: r = rsqrt(xs^2 A + xs twoB + Cc), tt = xs*r
//   v[d] = tt*a[d] + r*bb[d] + P[d],  P = [pB(w) | Bf(f)]
//   mu  = tt*sa8 + r*sb8 + pBsum8 + Bfsum8
//   s2/8= tt^2 caa8 + r^2 cbb8 + tt*r*cab8 + tt*(twoapB8+F5) + r*(twobpB8+F6) + (pB28eps+F7)
//   dt  = tt*ca + r*cb + pBdot + Bfdot
//   l   = r2*(dt - mu*swlg) + cK ;  pp = masked?0:exp(l); cf = pp*r2
//   av[d] = ctt*a + crr*bb + (d<4 ? SC*pB : avB) ; q = lg*invS*(av - smu)
//   out[p] = c2[p] + sum_d M[p][d] q[d]
__global__ __launch_bounds__(THREADS) void misstsm_fused(
    const float* __restrict__ x, const int* __restrict__ m,
    const float* __restrict__ emb_w, const float* __restrict__ emb_b,
    const float* __restrict__ emb_ln_g, const float* __restrict__ emb_ln_b,
    const float* __restrict__ ln_g, const float* __restrict__ ln_b,
    const float* __restrict__ var_query,
    const float* __restrict__ in_proj_w, const float* __restrict__ in_proj_b,
    const float* __restrict__ out_proj_w, const float* __restrict__ out_proj_b,
    const float* __restrict__ proj_w, const float* __restrict__ proj_b,
    float* __restrict__ out, int npos)
{
    __shared__ float s_M[64];      // (P O Wv)[p][d]
    __shared__ float s_c2[8];
    __shared__ float s_a[8], s_bb[8], s_wlg[8], s_lg[8];
    __shared__ float s_F[8][12];   // per-f: Bf[4], Bfsum8, F5, F6, F7, Bfdot
    __shared__ float s_sc[12];     // A,twoB,Cc, swlg,cK, sa8,sb8, caa8,cbb8,cab8, ca,cb

    const int t = threadIdx.x;
    const int pos = blockIdx.x * THREADS + t;

    // ---- prefetch this thread's data FIRST (hides latency under precompute) ----
    const float4* xv4 = reinterpret_cast<const float4*>(x);
    const int4*   mv4 = reinterpret_cast<const int4*>(m);
    const float4 xa = xv4[pos*2+0];
    const float4 xb = xv4[pos*2+1];
    const int4   ma = mv4[pos*2+0];
    const int4   mb = mv4[pos*2+1];

    // ---- per-block precompute, balanced across the 4 waves, ONE sync ----
    if (t < 64) {
        // wave0: M[p][d]
        const int p = t >> 3, d = t & 7;
        float acc = 0.0f;
        #pragma unroll
        for (int e = 0; e < 8; ++e) {
            float po = 0.0f;
            #pragma unroll
            for (int o = 0; o < 8; ++o) po = fmaf(proj_w[p*8+o], out_proj_w[o*8+e], po);
            acc = fmaf(po, in_proj_w[(16+e)*8 + d], acc);
        }
        s_M[t] = acc;
    } else if (t < 72) {
        // wave1a: wlg[d], lg[d]
        const int d = t - 64;
        float wk = 0.0f;
        #pragma unroll
        for (int e = 0; e < 8; ++e) {
            float qe = in_proj_b[e];
            #pragma unroll
            for (int dd = 0; dd < 8; ++dd) qe = fmaf(in_proj_w[e*8+dd], var_query[dd], qe);
            wk = fmaf(in_proj_w[(8+e)*8 + d], qe, wk);
        }
        s_wlg[d] = ln_g[d] * wk * INV_SQRT8;
        s_lg[d]  = ln_g[d];
    } else if (t < 80) {
        // wave1b: a[d], bb[d]
        const int d = t - 72;
        float ewm = 0.0f, ebm = 0.0f;
        #pragma unroll
        for (int dd = 0; dd < 8; ++dd) { ewm += emb_w[dd]; ebm += emb_b[dd]; }
        ewm *= 0.125f; ebm *= 0.125f;
        s_a[d]  = (emb_w[d] - ewm) * emb_ln_g[d];
        s_bb[d] = (emb_b[d] - ebm) * emb_ln_g[d];
    } else if (t == 80) {
        // wave1c: LN1 quadratic constants
        float ewm = 0.0f, ebm = 0.0f;
        #pragma unroll
        for (int d = 0; d < 8; ++d) { ewm += emb_w[d]; ebm += emb_b[d]; }
        ewm *= 0.125f; ebm *= 0.125f;
        float A = 0.0f, Bc = 0.0f, Cc = 0.0f;
        #pragma unroll
        for (int d = 0; d < 8; ++d) {
            const float dw = emb_w[d] - ewm, db = emb_b[d] - ebm;
            A = fmaf(dw, dw, A); Bc = fmaf(dw, db, Bc); Cc = fmaf(db, db, Cc);
        }
        s_sc[0] = A * 0.125f;
        s_sc[1] = 2.0f * Bc * 0.125f;
        s_sc[2] = Cc * 0.125f + 1e-5f;
    } else if (t >= 128 && t < 136) {
        // wave2a: c2[p]
        const int p = t - 128;
        float c = proj_b[p];
        #pragma unroll
        for (int o = 0; o < 8; ++o) {
            float ob2 = out_proj_b[o];
            #pragma unroll
            for (int e = 0; e < 8; ++e) ob2 = fmaf(out_proj_w[o*8+e], in_proj_b[16+e], ob2);
            c = fmaf(proj_w[p*8+o], ob2, c);
        }
        #pragma unroll
        for (int e = 0; e < 8; ++e) {
            float po = 0.0f;
            #pragma unroll
            for (int o = 0; o < 8; ++o) po = fmaf(proj_w[p*8+o], out_proj_w[o*8+e], po);
            #pragma unroll
            for (int d = 0; d < 8; ++d)
                c = fmaf(po * in_proj_w[(16+e)*8 + d], ln_b[d], c);
        }
        s_c2[p] = c;
    } else if (t == 136) {
        // wave2b: all dot-product scalars
        float qv[8]; float bkq = 0.0f;
        #pragma unroll
        for (int e = 0; e < 8; ++e) {
            float qe = in_proj_b[e];
            #pragma unroll
            for (int dd = 0; dd < 8; ++dd) qe = fmaf(in_proj_w[e*8+dd], var_query[dd], qe);
            qv[e] = qe;
            bkq = fmaf(in_proj_b[8+e], qe, bkq);
        }
        float ewm = 0.0f, ebm = 0.0f;
        #pragma unroll
        for (int d = 0; d < 8; ++d) { ewm += emb_w[d]; ebm += emb_b[d]; }
        ewm *= 0.125f; ebm *= 0.125f;
        float sa = 0, sb = 0, caa = 0, cbb = 0, cab = 0, ca = 0, cb = 0, sw = 0, ck = 0;
        #pragma unroll
        for (int d = 0; d < 8; ++d) {
            const float ad = (emb_w[d] - ewm) * emb_ln_g[d];
            const float bd = (emb_b[d] - ebm) * emb_ln_g[d];
            float wk = 0.0f;
            #pragma unroll
            for (int e = 0; e < 8; ++e) wk = fmaf(in_proj_w[(8+e)*8 + d], qv[e], wk);
            const float wl = ln_g[d] * wk * INV_SQRT8;
            sa += ad; sb += bd;
            caa = fmaf(ad, ad, caa); cbb = fmaf(bd, bd, cbb); cab = fmaf(ad, bd, cab);
            ca  = fmaf(ad, wl, ca);  cb  = fmaf(bd, wl, cb);
            sw += wl;
            ck  = fmaf(ln_b[d], wk, ck);
        }
        s_sc[3]  = sw;                         // swlg
        s_sc[4]  = (ck + bkq) * INV_SQRT8;     // cK
        s_sc[5]  = sa * 0.125f;                // sa8
        s_sc[6]  = sb * 0.125f;                // sb8
        s_sc[7]  = caa * 0.125f;               // caa8
        s_sc[8]  = cbb * 0.125f;               // cbb8
        s_sc[9]  = cab * 0.25f;                // cab8 (2/8)
        s_sc[10] = ca;
        s_sc[11] = cb;
    } else if (t >= 192 && t < 200) {
        // wave3: per-f table (trig + dot constants)
        const int f = t - 192;
        const float ff = (float)f;
        float sy0, cy0, sy1, cy1;
        sincosf(ff, &sy0, &cy0);
        sincosf(0.01f * ff, &sy1, &cy1);
        float Bf[4];
        Bf[0] = emb_ln_b[4] + sy0; Bf[1] = emb_ln_b[5] + cy0;
        Bf[2] = emb_ln_b[6] + sy1; Bf[3] = emb_ln_b[7] + cy1;
        float ewm = 0.0f, ebm = 0.0f;
        #pragma unroll
        for (int d = 0; d < 8; ++d) { ewm += emb_w[d]; ebm += emb_b[d]; }
        ewm *= 0.125f; ebm *= 0.125f;
        float qv[8];
        #pragma unroll
        for (int e = 0; e < 8; ++e) {
            float qe = in_proj_b[e];
            #pragma unroll
            for (int dd = 0; dd < 8; ++dd) qe = fmaf(in_proj_w[e*8+dd], var_query[dd], qe);
            qv[e] = qe;
        }
        float bsum = 0, aB = 0, bB = 0, b2 = 0, bdot = 0;
        #pragma unroll
        for (int j = 0; j < 4; ++j) {
            const int d = 4 + j;
            const float ad = (emb_w[d] - ewm) * emb_ln_g[d];
            const float bd = (emb_b[d] - ebm) * emb_ln_g[d];
            float wk = 0.0f;
            #pragma unroll
            for (int e = 0; e < 8; ++e) wk = fmaf(in_proj_w[(8+e)*8 + d], qv[e], wk);
            const float wl = ln_g[d] * wk * INV_SQRT8;
            bsum += Bf[j];
            aB  = fmaf(ad, Bf[j], aB);
            bB  = fmaf(bd, Bf[j], bB);
            b2  = fmaf(Bf[j], Bf[j], b2);
            bdot = fmaf(wl, Bf[j], bdot);
            s_F[f][j] = Bf[j];
        }
        s_F[f][4] = bsum * 0.125f;   // Bfsum8
        s_F[f][5] = aB * 0.25f;      // 2*aB/8
        s_F[f][6] = bB * 0.25f;
        s_F[f][7] = b2 * 0.125f;
        s_F[f][8] = bdot;
    }
    __syncthreads();

    if (pos >= npos) return;
    const int w = pos & (W_DIM - 1);

    const float xf[8] = {xa.x, xa.y, xa.z, xa.w, xb.x, xb.y, xb.z, xb.w};
    const int mk = (ma.x!=0?1:0) | (ma.y!=0?2:0) | (ma.z!=0?4:0) | (ma.w!=0?8:0)
                 | (mb.x!=0?16:0) | (mb.y!=0?32:0) | (mb.z!=0?64:0) | (mb.w!=0?128:0);

    const float A    = s_sc[0], twoB = s_sc[1], Cc  = s_sc[2];
    const float swlg = s_sc[3], cK   = s_sc[4];
    const float sa8  = s_sc[5], sb8  = s_sc[6];
    const float caa8 = s_sc[7], cbb8 = s_sc[8], cab8 = s_sc[9];
    const float ca   = s_sc[10], cb  = s_sc[11];

    // per-thread w-dependent constants
    const float fw = (float)w;
    float s1, c1, sl, clo;
    sincosf(fw, &s1, &c1);
    sincosf(0.01f * fw, &sl, &clo);
    float pB[4];
    pB[0] = emb_ln_b[0] + s1;  pB[1] = emb_ln_b[1] + c1;
    pB[2] = emb_ln_b[2] + sl;  pB[3] = emb_ln_b[3] + clo;

    float pBsum = 0, apB = 0, bpB = 0, pB2 = 0, pBdot = 0;
    #pragma unroll
    for (int j = 0; j < 4; ++j) {
        pBsum += pB[j];
        apB  = fmaf(s_a[j],  pB[j], apB);
        bpB  = fmaf(s_bb[j], pB[j], bpB);
        pB2  = fmaf(pB[j],  pB[j], pB2);
        pBdot = fmaf(s_wlg[j], pB[j], pBdot);
    }
    const float pBsum8  = pBsum * 0.125f;
    const float twoapB8 = apB * 0.25f;
    const float twobpB8 = bpB * 0.25f;
    const float pB28eps = fmaf(pB2, 0.125f, 1e-5f);

    float S = 0, SC = 0, ctt = 0, crr = 0, smu = 0;
    float avB[4] = {0, 0, 0, 0};

    #pragma unroll
    for (int f = 0; f < 8; ++f) {
        const float F0 = s_F[f][0], F1 = s_F[f][1], F2 = s_F[f][2], F3 = s_F[f][3];
        const float F4 = s_F[f][4], F5 = s_F[f][5], F6 = s_F[f][6], F7 = s_F[f][7];
        const float F8 = s_F[f][8];
        const float xs = xf[f];
        const float r  = rsqrtf(fmaf(xs, fmaf(xs, A, twoB), Cc));
        const float tt = xs * r;
        const float mu = fmaf(tt, sa8, fmaf(r, sb8, pBsum8 + F4));
        const float e1 = twoapB8 + F5;
        const float e2 = twobpB8 + F6;
        const float e3 = pB28eps + F7;
        const float s2v = fmaf(tt, fmaf(tt, caa8, fmaf(r, cab8, e1)),
                               fmaf(r, fmaf(r, cbb8, e2), e3));
        const float var = fmaf(-mu, mu, s2v);
        const float r2  = rsqrtf(var);
        const float dt  = fmaf(tt, ca, fmaf(r, cb, pBdot + F8));
        const float l   = fmaf(r2, fmaf(-mu, swlg, dt), cK);
        const float e   = __expf(l);
        const float pp  = ((mk >> f) & 1) ? 0.0f : e;
        const float cf  = pp * r2;
        S += pp; SC += cf;
        ctt = fmaf(cf, tt, ctt);
        crr = fmaf(cf, r,  crr);
        smu = fmaf(cf, mu, smu);
        avB[0] = fmaf(cf, F0, avB[0]);
        avB[1] = fmaf(cf, F1, avB[1]);
        avB[2] = fmaf(cf, F2, avB[2]);
        avB[3] = fmaf(cf, F3, avB[3]);
    }

    const float invS = 1.0f / S;
    float q[8];
    #pragma unroll
    for (int j = 0; j < 4; ++j) {
        const float av = fmaf(ctt, s_a[j], fmaf(crr, s_bb[j], SC * pB[j]));
        q[j] = s_lg[j] * invS * (av - smu);
    }
    #pragma unroll
    for (int j = 0; j < 4; ++j) {
        const float av = fmaf(ctt, s_a[4+j], fmaf(crr, s_bb[4+j], avB[j]));
        q[4+j] = s_lg[4+j] * invS * (av - smu);
    }

    float o[8];
    #pragma unroll
    for (int p = 0; p < 8; ++p) {
        float dp = s_c2[p];
        #pragma unroll
        for (int d = 0; d < 8; ++d) dp = fmaf(s_M[p*8+d], q[d], dp);
        o[p] = dp;
    }
    float4* ov4 = reinterpret_cast<float4*>(out);
    ov4[pos*2+0] = make_float4(o[0], o[1], o[2], o[3]);
    ov4[pos*2+1] = make_float4(o[4], o[5], o[6], o[7]);
}

extern "C" void kernel_launch(void* const* d_in, const int* in_sizes, int n_in,
                              void* d_out, int out_size, void* d_ws, size_t ws_size,
                              hipStream_t stream) {
    const float* x          = (const float*)d_in[0];
    const int*   m          = (const int*)d_in[1];
    const float* emb_w      = (const float*)d_in[2];
    const float* emb_b      = (const float*)d_in[3];
    const float* emb_ln_g   = (const float*)d_in[4];
    const float* emb_ln_b   = (const float*)d_in[5];
    const float* ln_g       = (const float*)d_in[6];
    const float* ln_b       = (const float*)d_in[7];
    const float* var_query  = (const float*)d_in[8];
    const float* in_proj_w  = (const float*)d_in[9];
    const float* in_proj_b  = (const float*)d_in[10];
    const float* out_proj_w = (const float*)d_in[11];
    const float* out_proj_b = (const float*)d_in[12];
    const float* proj_w     = (const float*)d_in[13];
    const float* proj_b     = (const float*)d_in[14];
    float* out = (float*)d_out;

    const int npos = in_sizes[0] / 8;                 // 262144
    const int grid = (npos + THREADS - 1) / THREADS;  // 1024
    misstsm_fused<<<grid, THREADS, 0, stream>>>(
        x, m, emb_w, emb_b, emb_ln_g, emb_ln_b, ln_g, ln_b, var_query,
        in_proj_w, in_proj_b, out_proj_w, out_proj_b, proj_w, proj_b,
        out, npos);
}